// Round 6
// baseline (1842.981 us; speedup 1.0000x reference)
//
#include <hip/hip_runtime.h>

#define N_PIX   (32 * 64 * 64)          // 131072 pixel rows
#define E_DIM   64
#define N_E     1024
#define Z_ELEMS (N_PIX * E_DIM)         // 8388608

#define LOSS_OFF 0
#define ZQ_OFF   1
#define PERP_OFF (1 + Z_ELEMS)                          // 8388609
#define ENC_OFF  ((size_t)(2 + Z_ELEMS))                // 8388610
#define IDX_OFF  (ENC_OFF + (size_t)N_PIX * N_E)        // 142606338

typedef float f32x2 __attribute__((ext_vector_type(2)));
typedef float f32x4 __attribute__((ext_vector_type(4)));

// DPP cross-lane adds within each 4-lane group (VALU pipe, no LDS traffic).
__device__ __forceinline__ float dpp_add_xor1(float v) {
    int i = __builtin_bit_cast(int, v);
    i = __builtin_amdgcn_mov_dpp(i, 0xB1, 0xF, 0xF, true);  // quad_perm(1,0,3,2)
    return v + __builtin_bit_cast(float, i);
}
__device__ __forceinline__ float dpp_add_xor2(float v) {
    int i = __builtin_bit_cast(int, v);
    i = __builtin_amdgcn_mov_dpp(i, 0x4E, 0xF, 0xF, true);  // quad_perm(2,3,0,1)
    return v + __builtin_bit_cast(float, i);
}

// ---- precompute ||e||^2 per codebook row ----
__global__ void vq_prep(const float* __restrict__ emb, float* __restrict__ ee) {
    int e = blockIdx.x * blockDim.x + threadIdx.x;
    if (e < N_E) {
        const float* r = emb + e * E_DIM;
        float s0 = 0.f, s1 = 0.f, s2 = 0.f, s3 = 0.f;
        #pragma unroll
        for (int c = 0; c < E_DIM; c += 4) {
            s0 = fmaf(r[c],     r[c],     s0);
            s1 = fmaf(r[c + 1], r[c + 1], s1);
            s2 = fmaf(r[c + 2], r[c + 2], s2);
            s3 = fmaf(r[c + 3], r[c + 3], s3);
        }
        ee[e] = (s0 + s1) + (s2 + s3);
    }
}

// ---- main: 4 lanes per pixel (16 channels each), depth-3 emb prefetch ----
// R5 failure mode: emb quarter-row loaded at use -> L1-thrash L2 latency (~300cy)
// exposed every iteration (VALUBusy 15%). Fix: 4 rotating register buffers,
// load code e+3 while computing code e. Live VGPRs ~96 < 128 cap -> 4 waves/SIMD.
__global__ __launch_bounds__(256, 4) void vq_main(
    const float* __restrict__ z, const float* __restrict__ emb,
    const float* __restrict__ ee, float* __restrict__ out,
    unsigned* __restrict__ counts, double* __restrict__ loss_acc)
{
    const int tid = threadIdx.x;
    const int s   = tid & 3;                  // channel quarter 0..3
    const int pl  = tid >> 2;                 // local pixel 0..63
    const int p   = blockIdx.x * 64 + pl;     // global pixel = b*4096 + hw
    const int b   = p >> 12;
    const int hw  = p & 4095;
    const int c0  = s << 4;                   // first channel of my quarter

    // ---- load my 16 channels of z (strided 4096 floats; coalesced per instr) ----
    const float* zp = z + ((size_t)b * E_DIM + c0) * 4096 + hw;
    f32x4 zv[4];
    #pragma unroll
    for (int j = 0; j < 4; ++j) {
        zv[j][0] = zp[(size_t)(4 * j    ) * 4096];
        zv[j][1] = zp[(size_t)(4 * j + 1) * 4096];
        zv[j][2] = zp[(size_t)(4 * j + 2) * 4096];
        zv[j][3] = zp[(size_t)(4 * j + 3) * 4096];
    }

    // ---- zz = ||z_row||^2 (must stay in d: reference tie-quantization, R4) ----
    f32x4 zacc = {0.f, 0.f, 0.f, 0.f};
    #pragma unroll
    for (int j = 0; j < 4; ++j)
        zacc = __builtin_elementwise_fma(zv[j], zv[j], zacc);
    f32x2 zt = __builtin_shufflevector(zacc, zacc, 0, 1)
             + __builtin_shufflevector(zacc, zacc, 2, 3);
    float zz = zt.x + zt.y;
    zz = dpp_add_xor1(zz);
    zz = dpp_add_xor2(zz);      // all 4 lanes hold full 64-ch zz

    // ---- argmin over codes, software-pipelined emb loads (depth 3) ----
    const float* ebase = emb + c0;
    float dmin = 3.4e38f;
    int   best = 0;

    f32x4 b0[4], b1[4], b2[4], b3[4];

    auto loadq = [&](f32x4* dst, int ei) {
        const f32x4* er = (const f32x4*)(ebase + (ei << 6));
        dst[0] = er[0]; dst[1] = er[1]; dst[2] = er[2]; dst[3] = er[3];
    };
    auto step = [&](const f32x4* cur, int ei) {
        f32x4 acc = {0.f, 0.f, 0.f, 0.f};
        #pragma unroll
        for (int j = 0; j < 4; ++j)
            acc = __builtin_elementwise_fma(zv[j], cur[j], acc);  // v_pk_fma_f32
        f32x2 t2 = __builtin_shufflevector(acc, acc, 0, 1)
                 + __builtin_shufflevector(acc, acc, 2, 3);
        float dot = t2.x + t2.y;      // my 16-ch partial
        dot = dpp_add_xor1(dot);      // + partner lane
        dot = dpp_add_xor2(dot);      // full 64-ch dot in all 4 lanes
        const float d = zz + ee[ei] - 2.0f * dot;   // reference-matching rounding
        if (d < dmin) { dmin = d; best = ei; }      // strict < = first-index ties
    };

    loadq(b0, 0); loadq(b1, 1); loadq(b2, 2);
    int e = 0;
    #pragma unroll 1
    for (; e < N_E - 6; e += 4) {
        loadq(b3, e + 3); step(b0, e);
        loadq(b0, e + 4); step(b1, e + 1);
        loadq(b1, e + 5); step(b2, e + 2);
        loadq(b2, e + 6); step(b3, e + 3);
    }
    // e == 1020 here: b0=1020, b1=1021, b2=1022 in flight; 1023 not yet loaded.
    loadq(b3, N_E - 1);
    step(b0, 1020); step(b1, 1021); step(b2, 1022); step(b3, 1023);

    // ---- index + histogram (group leader only; best is uniform in group) ----
    if (s == 0) {
        out[IDX_OFF + p] = (float)best;
        atomicAdd(&counts[best], 1u);
    }

    // ---- z_q (NCHW, NT stores) + loss partial over my 16 channels ----
    const f32x4* eb = (const f32x4*)(emb + (best << 6) + c0);
    float* zqp = out + ZQ_OFF + ((size_t)b * E_DIM + c0) * 4096 + hw;
    f32x4 lacc = {0.f, 0.f, 0.f, 0.f};
    #pragma unroll
    for (int j = 0; j < 4; ++j) {
        f32x4 q = eb[j];
        __builtin_nontemporal_store(q[0], &zqp[(size_t)(4 * j    ) * 4096]);
        __builtin_nontemporal_store(q[1], &zqp[(size_t)(4 * j + 1) * 4096]);
        __builtin_nontemporal_store(q[2], &zqp[(size_t)(4 * j + 2) * 4096]);
        __builtin_nontemporal_store(q[3], &zqp[(size_t)(4 * j + 3) * 4096]);
        f32x4 dq = q - zv[j];
        lacc = __builtin_elementwise_fma(dq, dq, lacc);
    }
    f32x2 lt = __builtin_shufflevector(lacc, lacc, 0, 1)
             + __builtin_shufflevector(lacc, lacc, 2, 3);
    float lsum = lt.x + lt.y;
    #pragma unroll
    for (int o = 32; o > 0; o >>= 1) lsum += __shfl_down(lsum, o);
    if ((tid & 63) == 0) atomicAdd(loss_acc, (double)lsum);

    // ---- one-hot: block cooperatively writes its 64 rows, coalesced NT ----
    // ENC_OFF % 4 == 2 elements -> only 8B-aligned; two f32x2 stores per row.
    __shared__ int sbest[64];
    if (s == 0) sbest[pl] = best;
    __syncthreads();
    const size_t blockbase = ENC_OFF + (size_t)blockIdx.x * 64 * N_E;
    const int col = tid * 4;
    for (int r = 0; r < 64; ++r) {
        const int rb = sbest[r];
        f32x2 v0 = { rb == col     ? 1.f : 0.f, rb == col + 1 ? 1.f : 0.f };
        f32x2 v1 = { rb == col + 2 ? 1.f : 0.f, rb == col + 3 ? 1.f : 0.f };
        float* dst = out + blockbase + (size_t)r * N_E + col;
        __builtin_nontemporal_store(v0, (f32x2*)dst);
        __builtin_nontemporal_store(v1, (f32x2*)(dst + 2));
    }
}

// ---- finalize: perplexity + loss ----
__global__ void vq_final(const unsigned* __restrict__ counts,
                         const double* __restrict__ loss_acc,
                         float* __restrict__ out)
{
    __shared__ float red[N_E];
    const int e = threadIdx.x;
    const float em = (float)counts[e] * (1.0f / (float)N_PIX);
    red[e] = em * logf(em + 1e-10f);
    __syncthreads();
    for (int s = 512; s > 0; s >>= 1) {
        if (e < s) red[e] += red[e + s];
        __syncthreads();
    }
    if (e == 0) {
        out[PERP_OFF] = expf(-red[0]);
        out[LOSS_OFF] = (float)((*loss_acc) * (1.25 / (double)Z_ELEMS));
    }
}

extern "C" void kernel_launch(void* const* d_in, const int* in_sizes, int n_in,
                              void* d_out, int out_size, void* d_ws, size_t ws_size,
                              hipStream_t stream) {
    const float* z   = (const float*)d_in[0];
    const float* emb = (const float*)d_in[1];
    float* out = (float*)d_out;

    unsigned* counts   = (unsigned*)d_ws;                   // 4096 B
    double*   loss_acc = (double*)((char*)d_ws + 4096);     // 8 B
    float*    ee       = (float*)((char*)d_ws + 8192);      // 4096 B

    (void)hipMemsetAsync(d_ws, 0, 4104, stream);
    vq_prep<<<4, 256, 0, stream>>>(emb, ee);
    vq_main<<<N_PIX / 64, 256, 0, stream>>>(z, emb, ee, out, counts, loss_acc);
    vq_final<<<1, N_E, 0, stream>>>(counts, loss_acc, out);
}

// Round 7
// 486.879 us; speedup vs baseline: 3.7853x; 3.7853x over previous
//
#include <hip/hip_runtime.h>

#define N_PIX   (32 * 64 * 64)          // 131072 pixel rows
#define E_DIM   64
#define N_E     1024
#define Z_ELEMS (N_PIX * E_DIM)         // 8388608
#define TC      64                      // codes per LDS tile
#define NT      (N_E / TC)              // 16 tiles

#define LOSS_OFF 0
#define ZQ_OFF   1
#define PERP_OFF (1 + Z_ELEMS)                          // 8388609
#define ENC_OFF  ((size_t)(2 + Z_ELEMS))                // 8388610
#define IDX_OFF  (ENC_OFF + (size_t)N_PIX * N_E)        // 142606338

typedef float f32x2 __attribute__((ext_vector_type(2)));
typedef float f32x4 __attribute__((ext_vector_type(4)));

// pair-exchange add: v + partner(v) across lanes (0,1),(2,3),... (VALU pipe)
__device__ __forceinline__ float dpp_add_xor1(float v) {
    int i = __builtin_bit_cast(int, v);
    i = __builtin_amdgcn_mov_dpp(i, 0xB1, 0xF, 0xF, true);  // quad_perm(1,0,3,2)
    return v + __builtin_bit_cast(float, i);
}

// ---- precompute ||e||^2 per codebook row ----
__global__ void vq_prep(const float* __restrict__ emb, float* __restrict__ ee) {
    int e = blockIdx.x * blockDim.x + threadIdx.x;
    if (e < N_E) {
        const float* r = emb + e * E_DIM;
        float s0 = 0.f, s1 = 0.f, s2 = 0.f, s3 = 0.f;
        #pragma unroll
        for (int c = 0; c < E_DIM; c += 4) {
            s0 = fmaf(r[c],     r[c],     s0);
            s1 = fmaf(r[c + 1], r[c + 1], s1);
            s2 = fmaf(r[c + 2], r[c + 2], s2);
            s3 = fmaf(r[c + 3], r[c + 3], s3);
        }
        ee[e] = (s0 + s1) + (s2 + s3);
    }
}

// ---- main: 2 lanes/pixel, codebook LDS-tiled + double-buffered ----
// R6 lesson: register prefetch gets undone by the allocator; stage the
// codebook through LDS instead (latency absorbed by tile-level pipelining,
// broadcast ds_reads are conflict-free and deterministic).
__global__ __launch_bounds__(256, 4) void vq_main(
    const float* __restrict__ z, const float* __restrict__ emb,
    const float* __restrict__ ee, float* __restrict__ out,
    unsigned* __restrict__ counts, double* __restrict__ loss_acc)
{
    __shared__ float lds[2][TC * E_DIM];    // 2 x 16 KB
    __shared__ int   sbest[128];

    const int tid  = threadIdx.x;
    const int half = tid & 1;               // channel half: [0..31] or [32..63]
    const int pl   = tid >> 1;              // local pixel 0..127
    const int p    = blockIdx.x * 128 + pl; // global pixel = b*4096 + hw
    const int b    = p >> 12;
    const int hw   = p & 4095;

    // ---- my 32 channels of z (stride 4096; coalesced in 128B segments) ----
    const float* zp = z + ((size_t)b * E_DIM + half * 32) * 4096 + hw;
    f32x4 zv[8];
    #pragma unroll
    for (int m = 0; m < 8; ++m) {
        zv[m][0] = zp[(size_t)(4 * m    ) * 4096];
        zv[m][1] = zp[(size_t)(4 * m + 1) * 4096];
        zv[m][2] = zp[(size_t)(4 * m + 2) * 4096];
        zv[m][3] = zp[(size_t)(4 * m + 3) * 4096];
    }

    // ---- zz (same tree as R5: per-16ch-quarter chained accs, pair combine) ----
    f32x4 za0 = {0.f,0.f,0.f,0.f}, za1 = {0.f,0.f,0.f,0.f};
    #pragma unroll
    for (int j = 0; j < 4; ++j) {
        za0 = __builtin_elementwise_fma(zv[j],     zv[j],     za0);
        za1 = __builtin_elementwise_fma(zv[4 + j], zv[4 + j], za1);
    }
    const float zq0 = (za0[0] + za0[2]) + (za0[1] + za0[3]);
    const float zq1 = (za1[0] + za1[2]) + (za1[1] + za1[3]);
    float zz = dpp_add_xor1(zq0 + zq1);     // full 64-ch zz, both lanes

    // ---- argmin over codes, tile-by-tile (double-buffered LDS) ----
    float dmin = 3.4e38f;
    int   best = 0;
    f32x4 st[4];

    // prologue: stage tile 0
    {
        const f32x4* gt = (const f32x4*)emb;    // tile 0
        #pragma unroll
        for (int j = 0; j < 4; ++j) st[j] = gt[j * 256 + tid];
        f32x4* lt = (f32x4*)lds[0];
        #pragma unroll
        for (int j = 0; j < 4; ++j) lt[j * 256 + tid] = st[j];
    }
    __syncthreads();

    for (int t = 0; t < NT; ++t) {
        const int cur = t & 1;
        // T14: issue next tile's global loads BEFORE compute (latency hidden)
        if (t + 1 < NT) {
            const f32x4* gt = (const f32x4*)(emb + (t + 1) * (TC * E_DIM));
            #pragma unroll
            for (int j = 0; j < 4; ++j) st[j] = gt[j * 256 + tid];
        }
        const f32x4* rows = (const f32x4*)lds[cur];
        const float* eet  = ee + t * TC;
        #pragma unroll 4
        for (int k = 0; k < TC; ++k) {
            const f32x4* row = rows + k * 16 + half * 8;   // my 32-ch half
            f32x4 a0 = {0.f,0.f,0.f,0.f}, a1 = {0.f,0.f,0.f,0.f};
            #pragma unroll
            for (int j = 0; j < 4; ++j) {
                a0 = __builtin_elementwise_fma(zv[j],     row[j],     a0);
                a1 = __builtin_elementwise_fma(zv[4 + j], row[4 + j], a1);
            }
            const float d0 = (a0[0] + a0[2]) + (a0[1] + a0[3]);
            const float d1 = (a1[0] + a1[2]) + (a1[1] + a1[3]);
            const float dot = dpp_add_xor1(d0 + d1);        // full 64-ch dot
            const float d = zz + eet[k] - 2.0f * dot;       // ref-matching form
            if (d < dmin) { dmin = d; best = t * TC + k; }  // first-index ties
        }
        // write next tile into the other buffer, then one barrier per tile
        if (t + 1 < NT) {
            f32x4* lt = (f32x4*)lds[cur ^ 1];
            #pragma unroll
            for (int j = 0; j < 4; ++j) lt[j * 256 + tid] = st[j];
        }
        __syncthreads();
    }

    // ---- index + histogram (one lane per pixel) ----
    if (half == 0) {
        out[IDX_OFF + p] = (float)best;
        atomicAdd(&counts[best], 1u);
    }

    // ---- z_q (NCHW, NT stores) + loss partial over my 32 channels ----
    const f32x4* eb = (const f32x4*)(emb + best * E_DIM) + half * 8;
    float* zqp = out + ZQ_OFF + ((size_t)b * E_DIM + half * 32) * 4096 + hw;
    f32x4 la0 = {0.f,0.f,0.f,0.f}, la1 = {0.f,0.f,0.f,0.f};
    #pragma unroll
    for (int m = 0; m < 4; ++m) {
        f32x4 q = eb[m];
        __builtin_nontemporal_store(q[0], &zqp[(size_t)(4 * m    ) * 4096]);
        __builtin_nontemporal_store(q[1], &zqp[(size_t)(4 * m + 1) * 4096]);
        __builtin_nontemporal_store(q[2], &zqp[(size_t)(4 * m + 2) * 4096]);
        __builtin_nontemporal_store(q[3], &zqp[(size_t)(4 * m + 3) * 4096]);
        f32x4 dq = q - zv[m];
        la0 = __builtin_elementwise_fma(dq, dq, la0);
    }
    #pragma unroll
    for (int m = 4; m < 8; ++m) {
        f32x4 q = eb[m];
        __builtin_nontemporal_store(q[0], &zqp[(size_t)(4 * m    ) * 4096]);
        __builtin_nontemporal_store(q[1], &zqp[(size_t)(4 * m + 1) * 4096]);
        __builtin_nontemporal_store(q[2], &zqp[(size_t)(4 * m + 2) * 4096]);
        __builtin_nontemporal_store(q[3], &zqp[(size_t)(4 * m + 3) * 4096]);
        f32x4 dq = q - zv[m];
        la1 = __builtin_elementwise_fma(dq, dq, la1);
    }
    float lsum = ((la0[0] + la0[2]) + (la0[1] + la0[3]))
               + ((la1[0] + la1[2]) + (la1[1] + la1[3]));
    #pragma unroll
    for (int o = 32; o > 0; o >>= 1) lsum += __shfl_down(lsum, o);
    if ((tid & 63) == 0) atomicAdd(loss_acc, (double)lsum);

    // ---- one-hot: block writes its 128 rows cooperatively, coalesced NT ----
    if (half == 0) sbest[pl] = best;
    __syncthreads();
    const size_t blockbase = ENC_OFF + (size_t)blockIdx.x * 128 * N_E;
    const int col = tid * 4;
    for (int r = 0; r < 128; ++r) {
        const int rb = sbest[r];
        f32x2 v0 = { rb == col     ? 1.f : 0.f, rb == col + 1 ? 1.f : 0.f };
        f32x2 v1 = { rb == col + 2 ? 1.f : 0.f, rb == col + 3 ? 1.f : 0.f };
        float* dst = out + blockbase + (size_t)r * N_E + col;
        __builtin_nontemporal_store(v0, (f32x2*)dst);
        __builtin_nontemporal_store(v1, (f32x2*)(dst + 2));
    }
}

// ---- finalize: perplexity + loss ----
__global__ void vq_final(const unsigned* __restrict__ counts,
                         const double* __restrict__ loss_acc,
                         float* __restrict__ out)
{
    __shared__ float red[N_E];
    const int e = threadIdx.x;
    const float em = (float)counts[e] * (1.0f / (float)N_PIX);
    red[e] = em * logf(em + 1e-10f);
    __syncthreads();
    for (int s = 512; s > 0; s >>= 1) {
        if (e < s) red[e] += red[e + s];
        __syncthreads();
    }
    if (e == 0) {
        out[PERP_OFF] = expf(-red[0]);
        out[LOSS_OFF] = (float)((*loss_acc) * (1.25 / (double)Z_ELEMS));
    }
}

extern "C" void kernel_launch(void* const* d_in, const int* in_sizes, int n_in,
                              void* d_out, int out_size, void* d_ws, size_t ws_size,
                              hipStream_t stream) {
    const float* z   = (const float*)d_in[0];
    const float* emb = (const float*)d_in[1];
    float* out = (float*)d_out;

    unsigned* counts   = (unsigned*)d_ws;                   // 4096 B
    double*   loss_acc = (double*)((char*)d_ws + 4096);     // 8 B
    float*    ee       = (float*)((char*)d_ws + 8192);      // 4096 B

    (void)hipMemsetAsync(d_ws, 0, 4104, stream);
    vq_prep<<<4, 256, 0, stream>>>(emb, ee);
    vq_main<<<N_PIX / 128, 256, 0, stream>>>(z, emb, ee, out, counts, loss_acc);
    vq_final<<<1, N_E, 0, stream>>>(counts, loss_acc, out);
}

// Round 8
// 408.862 us; speedup vs baseline: 4.5076x; 1.1908x over previous
//
#include <hip/hip_runtime.h>

#define N_PIX   (32 * 64 * 64)          // 131072 pixel rows
#define E_DIM   64
#define N_E     1024
#define Z_ELEMS (N_PIX * E_DIM)         // 8388608
#define TC      64                      // codes per LDS tile
#define NT      (N_E / TC)              // 16 tiles
#define PPB     256                     // pixels per block (P=2 per thread)

#define LOSS_OFF 0
#define ZQ_OFF   1
#define PERP_OFF (1 + Z_ELEMS)                          // 8388609
#define ENC_OFF  ((size_t)(2 + Z_ELEMS))                // 8388610
#define IDX_OFF  (ENC_OFF + (size_t)N_PIX * N_E)        // 142606338

typedef float f32x2 __attribute__((ext_vector_type(2)));
typedef float f32x4 __attribute__((ext_vector_type(4)));

// pair-exchange add: v + partner(v) across lanes (0,1),(2,3),... (VALU pipe)
__device__ __forceinline__ float dpp_add_xor1(float v) {
    int i = __builtin_bit_cast(int, v);
    i = __builtin_amdgcn_mov_dpp(i, 0xB1, 0xF, 0xF, true);  // quad_perm(1,0,3,2)
    return v + __builtin_bit_cast(float, i);
}

// ---- precompute ||e||^2 per codebook row ----
__global__ void vq_prep(const float* __restrict__ emb, float* __restrict__ ee) {
    int e = blockIdx.x * blockDim.x + threadIdx.x;
    if (e < N_E) {
        const float* r = emb + e * E_DIM;
        float s0 = 0.f, s1 = 0.f, s2 = 0.f, s3 = 0.f;
        #pragma unroll
        for (int c = 0; c < E_DIM; c += 4) {
            s0 = fmaf(r[c],     r[c],     s0);
            s1 = fmaf(r[c + 1], r[c + 1], s1);
            s2 = fmaf(r[c + 2], r[c + 2], s2);
            s3 = fmaf(r[c + 3], r[c + 3], s3);
        }
        ee[e] = (s0 + s1) + (s2 + s3);
    }
}

// ---- main: 2 lanes/pixel, 2 pixels/thread, codebook LDS-tiled ----
// R7 was VALU-issue-bound: ~3.9 SIMD-cyc/px/code vs 2.0 FMA floor. P=2
// M-blocking shares each LDS row fetch across 2 pixels; dot tree per pixel
// is bit-identical to R7 (numerics proven). (256,2): full VGPR budget, the
// grid is only 2 blocks/CU anyway.
__global__ __launch_bounds__(256, 2) void vq_main(
    const float* __restrict__ z, const float* __restrict__ emb,
    const float* __restrict__ ee, float* __restrict__ out,
    unsigned* __restrict__ counts, double* __restrict__ loss_acc)
{
    __shared__ float lds[2][TC * E_DIM];    // 2 x 16 KB
    __shared__ int   sbest[PPB];

    const int tid  = threadIdx.x;
    const int half = tid & 1;               // channel half: [0..31] or [32..63]
    const int pl   = tid >> 1;              // local pixel 0..127
    const int p0   = blockIdx.x * PPB + pl; // pixels p0 and p0+128 (same image b)
    const int b    = p0 >> 12;
    const int hw   = p0 & 4095;             // second pixel: hw+128 (<4096 always)

    // ---- my 32 channels of z for both pixels (stride 4096; coalesced) ----
    const float* zp = z + ((size_t)b * E_DIM + half * 32) * 4096 + hw;
    f32x4 zv0[8], zv1[8];
    #pragma unroll
    for (int m = 0; m < 8; ++m) {
        #pragma unroll
        for (int q = 0; q < 4; ++q) {
            zv0[m][q] = zp[(size_t)(4 * m + q) * 4096];
            zv1[m][q] = zp[(size_t)(4 * m + q) * 4096 + 128];
        }
    }

    // ---- zz per pixel (identical tree to R7) ----
    float zz0, zz1;
    {
        f32x4 za0 = {0.f,0.f,0.f,0.f}, za1 = {0.f,0.f,0.f,0.f};
        #pragma unroll
        for (int j = 0; j < 4; ++j) {
            za0 = __builtin_elementwise_fma(zv0[j],     zv0[j],     za0);
            za1 = __builtin_elementwise_fma(zv0[4 + j], zv0[4 + j], za1);
        }
        zz0 = dpp_add_xor1(((za0[0] + za0[2]) + (za0[1] + za0[3]))
                         + ((za1[0] + za1[2]) + (za1[1] + za1[3])));
    }
    {
        f32x4 za0 = {0.f,0.f,0.f,0.f}, za1 = {0.f,0.f,0.f,0.f};
        #pragma unroll
        for (int j = 0; j < 4; ++j) {
            za0 = __builtin_elementwise_fma(zv1[j],     zv1[j],     za0);
            za1 = __builtin_elementwise_fma(zv1[4 + j], zv1[4 + j], za1);
        }
        zz1 = dpp_add_xor1(((za0[0] + za0[2]) + (za0[1] + za0[3]))
                         + ((za1[0] + za1[2]) + (za1[1] + za1[3])));
    }

    // ---- argmin over codes, tile-by-tile (double-buffered LDS) ----
    float dmin0 = 3.4e38f, dmin1 = 3.4e38f;
    int   best0 = 0, best1 = 0;
    f32x4 st[4];

    {   // prologue: stage tile 0
        const f32x4* gt = (const f32x4*)emb;
        #pragma unroll
        for (int j = 0; j < 4; ++j) st[j] = gt[j * 256 + tid];
        f32x4* lt = (f32x4*)lds[0];
        #pragma unroll
        for (int j = 0; j < 4; ++j) lt[j * 256 + tid] = st[j];
    }
    __syncthreads();

    for (int t = 0; t < NT; ++t) {
        const int cur = t & 1;
        if (t + 1 < NT) {   // T14: next tile's global loads BEFORE compute
            const f32x4* gt = (const f32x4*)(emb + (t + 1) * (TC * E_DIM));
            #pragma unroll
            for (int j = 0; j < 4; ++j) st[j] = gt[j * 256 + tid];
        }
        const f32x4* rows = (const f32x4*)lds[cur];
        const float* eet  = ee + t * TC;
        #pragma unroll 2
        for (int k = 0; k < TC; ++k) {
            f32x4 row[8];
            const f32x4* rp = rows + k * 16 + half * 8;
            #pragma unroll
            for (int j = 0; j < 8; ++j) row[j] = rp[j];

            // pixel 0 (R7 tree, unchanged)
            {
                f32x4 a0 = {0.f,0.f,0.f,0.f}, a1 = {0.f,0.f,0.f,0.f};
                #pragma unroll
                for (int j = 0; j < 4; ++j) {
                    a0 = __builtin_elementwise_fma(zv0[j],     row[j],     a0);
                    a1 = __builtin_elementwise_fma(zv0[4 + j], row[4 + j], a1);
                }
                const float d0 = (a0[0] + a0[2]) + (a0[1] + a0[3]);
                const float d1 = (a1[0] + a1[2]) + (a1[1] + a1[3]);
                const float dot = dpp_add_xor1(d0 + d1);
                const float d = zz0 + eet[k] - 2.0f * dot;
                if (d < dmin0) { dmin0 = d; best0 = t * TC + k; }
            }
            // pixel 1 (same tree)
            {
                f32x4 a0 = {0.f,0.f,0.f,0.f}, a1 = {0.f,0.f,0.f,0.f};
                #pragma unroll
                for (int j = 0; j < 4; ++j) {
                    a0 = __builtin_elementwise_fma(zv1[j],     row[j],     a0);
                    a1 = __builtin_elementwise_fma(zv1[4 + j], row[4 + j], a1);
                }
                const float d0 = (a0[0] + a0[2]) + (a0[1] + a0[3]);
                const float d1 = (a1[0] + a1[2]) + (a1[1] + a1[3]);
                const float dot = dpp_add_xor1(d0 + d1);
                const float d = zz1 + eet[k] - 2.0f * dot;
                if (d < dmin1) { dmin1 = d; best1 = t * TC + k; }
            }
        }
        if (t + 1 < NT) {
            f32x4* lt = (f32x4*)lds[cur ^ 1];
            #pragma unroll
            for (int j = 0; j < 4; ++j) lt[j * 256 + tid] = st[j];
        }
        __syncthreads();
    }

    // ---- index + histogram (one lane per pixel) ----
    if (half == 0) {
        out[IDX_OFF + p0]       = (float)best0;
        out[IDX_OFF + p0 + 128] = (float)best1;
        atomicAdd(&counts[best0], 1u);
        atomicAdd(&counts[best1], 1u);
    }

    // ---- z_q (NCHW, NT stores) + loss partials over my 32 channels ----
    float lsum;
    {
        const f32x4* eb0 = (const f32x4*)(emb + best0 * E_DIM) + half * 8;
        const f32x4* eb1 = (const f32x4*)(emb + best1 * E_DIM) + half * 8;
        float* zqp = out + ZQ_OFF + ((size_t)b * E_DIM + half * 32) * 4096 + hw;
        f32x4 la0 = {0.f,0.f,0.f,0.f}, la1 = {0.f,0.f,0.f,0.f};
        #pragma unroll
        for (int m = 0; m < 8; ++m) {
            f32x4 q0 = eb0[m], q1 = eb1[m];
            #pragma unroll
            for (int q = 0; q < 4; ++q) {
                __builtin_nontemporal_store(q0[q], &zqp[(size_t)(4 * m + q) * 4096]);
                __builtin_nontemporal_store(q1[q], &zqp[(size_t)(4 * m + q) * 4096 + 128]);
            }
            f32x4 dq0 = q0 - zv0[m], dq1 = q1 - zv1[m];
            la0 = __builtin_elementwise_fma(dq0, dq0, la0);
            la1 = __builtin_elementwise_fma(dq1, dq1, la1);
        }
        lsum = ((la0[0] + la0[2]) + (la0[1] + la0[3]))
             + ((la1[0] + la1[2]) + (la1[1] + la1[3]));
    }
    #pragma unroll
    for (int o = 32; o > 0; o >>= 1) lsum += __shfl_down(lsum, o);
    if ((tid & 63) == 0) atomicAdd(loss_acc, (double)lsum);

    // ---- one-hot: block writes its 256 rows cooperatively, coalesced NT ----
    if (half == 0) { sbest[pl] = best0; sbest[pl + 128] = best1; }
    __syncthreads();
    const size_t blockbase = ENC_OFF + (size_t)blockIdx.x * PPB * N_E;
    const int col = tid * 4;
    for (int r = 0; r < PPB; ++r) {
        const int rb = sbest[r];
        f32x2 v0 = { rb == col     ? 1.f : 0.f, rb == col + 1 ? 1.f : 0.f };
        f32x2 v1 = { rb == col + 2 ? 1.f : 0.f, rb == col + 3 ? 1.f : 0.f };
        float* dst = out + blockbase + (size_t)r * N_E + col;
        __builtin_nontemporal_store(v0, (f32x2*)dst);
        __builtin_nontemporal_store(v1, (f32x2*)(dst + 2));
    }
}

// ---- finalize: perplexity + loss ----
__global__ void vq_final(const unsigned* __restrict__ counts,
                         const double* __restrict__ loss_acc,
                         float* __restrict__ out)
{
    __shared__ float red[N_E];
    const int e = threadIdx.x;
    const float em = (float)counts[e] * (1.0f / (float)N_PIX);
    red[e] = em * logf(em + 1e-10f);
    __syncthreads();
    for (int s = 512; s > 0; s >>= 1) {
        if (e < s) red[e] += red[e + s];
        __syncthreads();
    }
    if (e == 0) {
        out[PERP_OFF] = expf(-red[0]);
        out[LOSS_OFF] = (float)((*loss_acc) * (1.25 / (double)Z_ELEMS));
    }
}

extern "C" void kernel_launch(void* const* d_in, const int* in_sizes, int n_in,
                              void* d_out, int out_size, void* d_ws, size_t ws_size,
                              hipStream_t stream) {
    const float* z   = (const float*)d_in[0];
    const float* emb = (const float*)d_in[1];
    float* out = (float*)d_out;

    unsigned* counts   = (unsigned*)d_ws;                   // 4096 B
    double*   loss_acc = (double*)((char*)d_ws + 4096);     // 8 B
    float*    ee       = (float*)((char*)d_ws + 8192);      // 4096 B

    (void)hipMemsetAsync(d_ws, 0, 4104, stream);
    vq_prep<<<4, 256, 0, stream>>>(emb, ee);
    vq_main<<<N_PIX / PPB, 256, 0, stream>>>(z, emb, ee, out, counts, loss_acc);
    vq_final<<<1, N_E, 0, stream>>>(counts, loss_acc, out);
}

// Round 9
// 377.520 us; speedup vs baseline: 4.8818x; 1.0830x over previous
//
#include <hip/hip_runtime.h>

#define N_PIX   (32 * 64 * 64)          // 131072 pixel rows
#define E_DIM   64
#define N_E     1024
#define Z_ELEMS (N_PIX * E_DIM)         // 8388608
#define TC      64                      // codes per LDS tile
#define NT      (N_E / TC)              // 16 tiles
#define PPB     128                     // pixels per block (4 lanes/px, P=2)

#define LOSS_OFF 0
#define ZQ_OFF   1
#define PERP_OFF (1 + Z_ELEMS)                          // 8388609
#define ENC_OFF  ((size_t)(2 + Z_ELEMS))                // 8388610
#define IDX_OFF  (ENC_OFF + (size_t)N_PIX * N_E)        // 142606338

typedef float f32x2 __attribute__((ext_vector_type(2)));
typedef float f32x4 __attribute__((ext_vector_type(4)));

// cross-lane adds within each 4-lane group (VALU pipe, no LDS traffic)
__device__ __forceinline__ float dpp_add_xor1(float v) {
    int i = __builtin_bit_cast(int, v);
    i = __builtin_amdgcn_mov_dpp(i, 0xB1, 0xF, 0xF, true);  // quad_perm(1,0,3,2)
    return v + __builtin_bit_cast(float, i);
}
__device__ __forceinline__ float dpp_add_xor2(float v) {
    int i = __builtin_bit_cast(int, v);
    i = __builtin_amdgcn_mov_dpp(i, 0x4E, 0xF, 0xF, true);  // quad_perm(2,3,0,1)
    return v + __builtin_bit_cast(float, i);
}

// ---- precompute ||e||^2 per codebook row ----
__global__ void vq_prep(const float* __restrict__ emb, float* __restrict__ ee) {
    int e = blockIdx.x * blockDim.x + threadIdx.x;
    if (e < N_E) {
        const float* r = emb + e * E_DIM;
        float s0 = 0.f, s1 = 0.f, s2 = 0.f, s3 = 0.f;
        #pragma unroll
        for (int c = 0; c < E_DIM; c += 4) {
            s0 = fmaf(r[c],     r[c],     s0);
            s1 = fmaf(r[c + 1], r[c + 1], s1);
            s2 = fmaf(r[c + 2], r[c + 2], s2);
            s3 = fmaf(r[c + 3], r[c + 3], s3);
        }
        ee[e] = (s0 + s1) + (s2 + s3);
    }
}

// ---- main: 4 lanes/pixel (R5's proven 16-ch tree), 2 px/thread, LDS tiles ----
// R8 was VALU-instr-bound (251us busy) at 1.6 waves/SIMD. 4-lane split cuts
// per-px-per-code VALU 30->20 instr (8 pk_fma + 12 tree) and doubles wave
// count to 4/SIMD. LDS b128 per pixel unchanged. Numerics: 16-ch quarter
// chains + quad DPP + (zz + ee - 2*dot) == R5's passing form exactly.
__global__ __launch_bounds__(256, 4) void vq_main(
    const float* __restrict__ z, const float* __restrict__ emb,
    const float* __restrict__ ee, float* __restrict__ out,
    unsigned* __restrict__ counts, double* __restrict__ loss_acc)
{
    __shared__ float lds[2][TC * E_DIM];    // 2 x 16 KB
    __shared__ int   sbest[PPB];

    const int tid = threadIdx.x;
    const int s   = tid & 3;                // channel quarter 0..3
    const int pl  = tid >> 2;               // local pixel 0..63
    const int p0  = blockIdx.x * PPB + pl;  // pixels p0 and p0+64 (same image)
    const int b   = p0 >> 12;
    const int hw  = p0 & 4095;              // second pixel at hw+64 (no wrap)

    // ---- my 16 channels of z for both pixels (stride 4096) ----
    const float* zp = z + ((size_t)b * E_DIM + s * 16) * 4096 + hw;
    f32x4 zv0[4], zv1[4];
    #pragma unroll
    for (int m = 0; m < 4; ++m) {
        #pragma unroll
        for (int q = 0; q < 4; ++q) {
            zv0[m][q] = zp[(size_t)(4 * m + q) * 4096];
            zv1[m][q] = zp[(size_t)(4 * m + q) * 4096 + 64];
        }
    }

    // ---- zz per pixel (R5 tree: chained vec-fma, pairwise combine, quad DPP) ----
    float zz0, zz1;
    {
        f32x4 za = {0.f,0.f,0.f,0.f};
        #pragma unroll
        for (int j = 0; j < 4; ++j) za = __builtin_elementwise_fma(zv0[j], zv0[j], za);
        f32x2 zt = __builtin_shufflevector(za, za, 0, 1)
                 + __builtin_shufflevector(za, za, 2, 3);
        zz0 = dpp_add_xor2(dpp_add_xor1(zt.x + zt.y));
    }
    {
        f32x4 za = {0.f,0.f,0.f,0.f};
        #pragma unroll
        for (int j = 0; j < 4; ++j) za = __builtin_elementwise_fma(zv1[j], zv1[j], za);
        f32x2 zt = __builtin_shufflevector(za, za, 0, 1)
                 + __builtin_shufflevector(za, za, 2, 3);
        zz1 = dpp_add_xor2(dpp_add_xor1(zt.x + zt.y));
    }

    // ---- argmin over codes, tile-by-tile (double-buffered LDS) ----
    float dmin0 = 3.4e38f, dmin1 = 3.4e38f;
    int   best0 = 0, best1 = 0;
    f32x4 st[4];

    {   // prologue: stage tile 0 (1024 f32x4 covered by 256 threads x4)
        const f32x4* gt = (const f32x4*)emb;
        #pragma unroll
        for (int j = 0; j < 4; ++j) st[j] = gt[j * 256 + tid];
        f32x4* lt = (f32x4*)lds[0];
        #pragma unroll
        for (int j = 0; j < 4; ++j) lt[j * 256 + tid] = st[j];
    }
    __syncthreads();

    for (int t = 0; t < NT; ++t) {
        const int cur = t & 1;
        if (t + 1 < NT) {   // T14: issue next tile's global loads BEFORE compute
            const f32x4* gt = (const f32x4*)(emb + (t + 1) * (TC * E_DIM));
            #pragma unroll
            for (int j = 0; j < 4; ++j) st[j] = gt[j * 256 + tid];
        }
        const f32x4* rows = (const f32x4*)lds[cur];
        const float* eet  = ee + t * TC;
        #pragma unroll 4
        for (int k = 0; k < TC; ++k) {
            f32x4 row[4];
            const f32x4* rp = rows + k * 16 + s * 4;   // my 16-ch quarter
            #pragma unroll
            for (int j = 0; j < 4; ++j) row[j] = rp[j];   // broadcast, 0-conflict

            // pixel 0 (R5 tree)
            {
                f32x4 a = {0.f,0.f,0.f,0.f};
                #pragma unroll
                for (int j = 0; j < 4; ++j) a = __builtin_elementwise_fma(zv0[j], row[j], a);
                f32x2 t2 = __builtin_shufflevector(a, a, 0, 1)
                         + __builtin_shufflevector(a, a, 2, 3);
                const float dot = dpp_add_xor2(dpp_add_xor1(t2.x + t2.y));
                const float d = zz0 + eet[k] - 2.0f * dot;
                if (d < dmin0) { dmin0 = d; best0 = t * TC + k; }
            }
            // pixel 1 (same tree)
            {
                f32x4 a = {0.f,0.f,0.f,0.f};
                #pragma unroll
                for (int j = 0; j < 4; ++j) a = __builtin_elementwise_fma(zv1[j], row[j], a);
                f32x2 t2 = __builtin_shufflevector(a, a, 0, 1)
                         + __builtin_shufflevector(a, a, 2, 3);
                const float dot = dpp_add_xor2(dpp_add_xor1(t2.x + t2.y));
                const float d = zz1 + eet[k] - 2.0f * dot;
                if (d < dmin1) { dmin1 = d; best1 = t * TC + k; }
            }
        }
        if (t + 1 < NT) {
            f32x4* lt = (f32x4*)lds[cur ^ 1];
            #pragma unroll
            for (int j = 0; j < 4; ++j) lt[j * 256 + tid] = st[j];
        }
        __syncthreads();
    }

    // ---- index + histogram (group leader; best uniform across the quad) ----
    if (s == 0) {
        out[IDX_OFF + p0]      = (float)best0;
        out[IDX_OFF + p0 + 64] = (float)best1;
        atomicAdd(&counts[best0], 1u);
        atomicAdd(&counts[best1], 1u);
    }

    // ---- z_q (NCHW, NT stores) + loss partials over my 16 channels ----
    float lsum;
    {
        const f32x4* eb0 = (const f32x4*)(emb + best0 * E_DIM) + s * 4;
        const f32x4* eb1 = (const f32x4*)(emb + best1 * E_DIM) + s * 4;
        float* zqp = out + ZQ_OFF + ((size_t)b * E_DIM + s * 16) * 4096 + hw;
        f32x4 la0 = {0.f,0.f,0.f,0.f}, la1 = {0.f,0.f,0.f,0.f};
        #pragma unroll
        for (int m = 0; m < 4; ++m) {
            f32x4 q0 = eb0[m], q1 = eb1[m];
            #pragma unroll
            for (int q = 0; q < 4; ++q) {
                __builtin_nontemporal_store(q0[q], &zqp[(size_t)(4 * m + q) * 4096]);
                __builtin_nontemporal_store(q1[q], &zqp[(size_t)(4 * m + q) * 4096 + 64]);
            }
            f32x4 dq0 = q0 - zv0[m], dq1 = q1 - zv1[m];
            la0 = __builtin_elementwise_fma(dq0, dq0, la0);
            la1 = __builtin_elementwise_fma(dq1, dq1, la1);
        }
        lsum = ((la0[0] + la0[2]) + (la0[1] + la0[3]))
             + ((la1[0] + la1[2]) + (la1[1] + la1[3]));
    }
    #pragma unroll
    for (int o = 32; o > 0; o >>= 1) lsum += __shfl_down(lsum, o);
    if ((tid & 63) == 0) atomicAdd(loss_acc, (double)lsum);

    // ---- one-hot: block writes its 128 rows cooperatively, coalesced NT ----
    if (s == 0) { sbest[pl] = best0; sbest[pl + 64] = best1; }
    __syncthreads();
    const size_t blockbase = ENC_OFF + (size_t)blockIdx.x * PPB * N_E;
    const int col = tid * 4;
    for (int r = 0; r < PPB; ++r) {
        const int rb = sbest[r];
        f32x2 v0 = { rb == col     ? 1.f : 0.f, rb == col + 1 ? 1.f : 0.f };
        f32x2 v1 = { rb == col + 2 ? 1.f : 0.f, rb == col + 3 ? 1.f : 0.f };
        float* dst = out + blockbase + (size_t)r * N_E + col;
        __builtin_nontemporal_store(v0, (f32x2*)dst);
        __builtin_nontemporal_store(v1, (f32x2*)(dst + 2));
    }
}

// ---- finalize: perplexity + loss ----
__global__ void vq_final(const unsigned* __restrict__ counts,
                         const double* __restrict__ loss_acc,
                         float* __restrict__ out)
{
    __shared__ float red[N_E];
    const int e = threadIdx.x;
    const float em = (float)counts[e] * (1.0f / (float)N_PIX);
    red[e] = em * logf(em + 1e-10f);
    __syncthreads();
    for (int s = 512; s > 0; s >>= 1) {
        if (e < s) red[e] += red[e + s];
        __syncthreads();
    }
    if (e == 0) {
        out[PERP_OFF] = expf(-red[0]);
        out[LOSS_OFF] = (float)((*loss_acc) * (1.25 / (double)Z_ELEMS));
    }
}

extern "C" void kernel_launch(void* const* d_in, const int* in_sizes, int n_in,
                              void* d_out, int out_size, void* d_ws, size_t ws_size,
                              hipStream_t stream) {
    const float* z   = (const float*)d_in[0];
    const float* emb = (const float*)d_in[1];
    float* out = (float*)d_out;

    unsigned* counts   = (unsigned*)d_ws;                   // 4096 B
    double*   loss_acc = (double*)((char*)d_ws + 4096);     // 8 B
    float*    ee       = (float*)((char*)d_ws + 8192);      // 4096 B

    (void)hipMemsetAsync(d_ws, 0, 4104, stream);
    vq_prep<<<4, 256, 0, stream>>>(emb, ee);
    vq_main<<<N_PIX / PPB, 256, 0, stream>>>(z, emb, ee, out, counts, loss_acc);
    vq_final<<<1, N_E, 0, stream>>>(counts, loss_acc, out);
}